// Round 8
// baseline (431.739 us; speedup 1.0000x reference)
//
#include <hip/hip_runtime.h>
#include <math.h>

#define K_CODES 1024
#define D_DIM   256
#define HW      1024          // 32*32
#define N_ROWS  32768
#define TAU     1.2e-4f       // ambiguity margin (quantized-score domain)

typedef __attribute__((ext_vector_type(8))) short bf16x8;
typedef __attribute__((ext_vector_type(4))) float f32x4;
#define MFMA16(a, b, c) __builtin_amdgcn_mfma_f32_16x16x32_bf16(a, b, c, 0, 0, 0)

__device__ __forceinline__ unsigned bf16_rne_bits(float x) {
    unsigned u = __float_as_uint(x);
    return (u + 0x7FFFu + ((u >> 16) & 1u)) >> 16;
}

// ---------- numpy-faithful pairwise sum of squares (validated round 2) ----------
__device__ __forceinline__ float pw_block128_sq(const float* a) {
    #pragma clang fp contract(off)
    float S[16];
    #pragma unroll
    for (int l = 0; l < 16; ++l) {
        float x0 = a[l],      x4 = a[64 + l];
        float x1 = a[16 + l], x5 = a[80 + l];
        float x2 = a[32 + l], x6 = a[96 + l];
        float x3 = a[48 + l], x7 = a[112 + l];
        float r0 = x0 * x0 + x4 * x4;
        float r1 = x1 * x1 + x5 * x5;
        float r2 = x2 * x2 + x6 * x6;
        float r3 = x3 * x3 + x7 * x7;
        S[l] = (r0 + r1) + (r2 + r3);
    }
    float u0 = S[0] + S[8],  u1 = S[1] + S[9],  u2 = S[2] + S[10], u3 = S[3] + S[11];
    float u4 = S[4] + S[12], u5 = S[5] + S[13], u6 = S[6] + S[14], u7 = S[7] + S[15];
    float v0 = u0 + u4, v1 = u1 + u5, v2 = u2 + u6, v3 = u3 + u7;
    return (v0 + v2) + (v1 + v3);
}
__device__ __forceinline__ float pw_sum256_sq(const float* a) {
    #pragma clang fp contract(off)
    float b0 = pw_block128_sq(a);
    float b1 = pw_block128_sq(a + 128);
    return b0 + b1;
}

// ---------------- K0: emb -> bf16 hi/lo split ----------------
__global__ void k_emb_cvt(const float* __restrict__ emb,
                          ushort* __restrict__ hi, ushort* __restrict__ lo) {
    int i = blockIdx.x * 256 + threadIdx.x;   // 65536 float4 groups
    float4 v = reinterpret_cast<const float4*>(emb)[i];
    ushort4 h, l;
    float x[4] = {v.x, v.y, v.z, v.w};
    ushort hb[4], lb[4];
    #pragma unroll
    for (int j = 0; j < 4; ++j) {
        unsigned hbits = bf16_rne_bits(x[j]);
        float hf = __uint_as_float(hbits << 16);
        unsigned lbits = bf16_rne_bits(x[j] - hf);
        hb[j] = (ushort)hbits; lb[j] = (ushort)lbits;
    }
    h.x = hb[0]; h.y = hb[1]; h.z = hb[2]; h.w = hb[3];
    l.x = lb[0]; l.y = lb[1]; l.z = lb[2]; l.w = lb[3];
    reinterpret_cast<ushort4*>(hi)[i] = h;
    reinterpret_cast<ushort4*>(lo)[i] = l;
}

// ---------------- K1: emb row norms (numpy-faithful) ----------------
__global__ void k_emb_norm(const float* __restrict__ emb, float* __restrict__ enorm) {
    int k = blockIdx.x * 256 + threadIdx.x;
    if (k < K_CODES) enorm[k] = pw_sum256_sq(emb + (size_t)k * D_DIM);
}

// ---------------- K2: MFMA screen ----------------
// Block: 256 thr (4 waves). 64 rows/block, wave owns 16 rows (A in VGPRs).
// K-loop over 64 tiles of 16 codes; B (hi/lo bf16) double-buffered in LDS.
// Scores s = fl(fl(zn+en) - 2*m); track best1/best2; flag gap<=TAU rows.
#define BT_STR 264              // padded ushort stride (16B-aligned rows)
#define BT_BLK (16 * BT_STR)    // one 16-code half-tile (hi or lo)
__global__ __launch_bounds__(256, 2) void k_screen_mfma(
    const float* __restrict__ z,
    const ushort* __restrict__ emb_hi, const ushort* __restrict__ emb_lo,
    const float* __restrict__ enorm, float* __restrict__ zn_row,
    int* __restrict__ idx_ws, int* __restrict__ worklist, int* __restrict__ nflag)
{
    __shared__ __align__(16) float zl[64 * 257];   // 65792 B; reused as B tiles
    __shared__ float enorm_lds[K_CODES];
    __shared__ float zn_sh[64];

    const int tid  = threadIdx.x;
    const int lane = tid & 63, wave = tid >> 6;
    const int blk  = blockIdx.x;                   // 512 blocks
    const int batch = blk >> 4;
    const int p0    = (blk & 15) * 64;
    const float* zb = z + (size_t)batch * D_DIM * HW;

    // stage z tile (f32): zl[p*257 + d] = z[batch][d][p0+p]
    {
        int p = tid & 63;
        for (int d = tid >> 6; d < D_DIM; d += 4)
            zl[p * 257 + d] = zb[(size_t)d * HW + p0 + p];
    }
    // stage enorm
    for (int i = tid; i < K_CODES; i += 256) enorm_lds[i] = enorm[i];
    __syncthreads();

    // numpy-faithful zn per row (also persisted for the recheck kernel)
    if (tid < 64) {
        float zn = pw_sum256_sq(&zl[tid * 257]);
        zn_sh[tid] = zn;
        zn_row[blk * 64 + tid] = zn;
    }

    // build A fragments in registers (hi/lo bf16), 16 rows per wave
    const int fr = lane & 15, fg = lane >> 4;
    bf16x8 Ah[8], Al[8];
    {
        const float* zr = &zl[(wave * 16 + fr) * 257];
        #pragma unroll
        for (int s = 0; s < 8; ++s) {
            int c0 = s * 32 + fg * 8;
            bf16x8 h, l;
            #pragma unroll
            for (int j = 0; j < 8; ++j) {
                float x = zr[c0 + j];
                unsigned hb = bf16_rne_bits(x);
                float hf = __uint_as_float(hb << 16);
                unsigned lb = bf16_rne_bits(x - hf);
                h[j] = (short)hb; l[j] = (short)lb;
            }
            Ah[s] = h; Al[s] = l;
        }
    }
    __syncthreads();   // zl (f32) dead; B tiles may now overwrite it

    ushort* bt = reinterpret_cast<ushort*>(zl);    // [2 buf][hi,lo][16][BT_STR]

    // stage helper: tile kt -> buffer buf
    auto stage = [&](int buf, int kt) {
        int row = tid >> 5, d16 = tid & 31;
        #pragma unroll
        for (int i = 0; i < 2; ++i) {
            int r = row + 8 * i;
            size_t src = ((size_t)(kt * 16 + r) << 8) + d16 * 8;
            uint4 vh = *reinterpret_cast<const uint4*>(emb_hi + src);
            uint4 vl = *reinterpret_cast<const uint4*>(emb_lo + src);
            *reinterpret_cast<uint4*>(&bt[(buf * 2 + 0) * BT_BLK + r * BT_STR + d16 * 8]) = vh;
            *reinterpret_cast<uint4*>(&bt[(buf * 2 + 1) * BT_BLK + r * BT_STR + d16 * 8]) = vl;
        }
    };

    float zn4[4];
    #pragma unroll
    for (int r = 0; r < 4; ++r) zn4[r] = zn_sh[wave * 16 + fg * 4 + r];

    float b1v[4] = {1e30f, 1e30f, 1e30f, 1e30f};
    float b2v[4] = {1e30f, 1e30f, 1e30f, 1e30f};
    int   b1i[4] = {0, 0, 0, 0};

    stage(0, 0);
    __syncthreads();

    const int boff = fr * BT_STR + fg * 8;
    for (int kt = 0; kt < 64; ++kt) {
        int cur = kt & 1;
        if (kt < 63) stage(cur ^ 1, kt + 1);

        f32x4 aHH = {0.f, 0.f, 0.f, 0.f};
        f32x4 aHM = {0.f, 0.f, 0.f, 0.f};
        f32x4 aLH = {0.f, 0.f, 0.f, 0.f};
        const ushort* bhp = bt + cur * 2 * BT_BLK + boff;
        const ushort* blp = bhp + BT_BLK;
        #pragma unroll
        for (int s = 0; s < 8; ++s) {
            bf16x8 Bh = *reinterpret_cast<const bf16x8*>(bhp + s * 32);
            bf16x8 Bl = *reinterpret_cast<const bf16x8*>(blp + s * 32);
            aHH = MFMA16(Ah[s], Bh, aHH);
            aHM = MFMA16(Ah[s], Bl, aHM);
            aLH = MFMA16(Al[s], Bh, aLH);
        }
        {
            #pragma clang fp contract(off)
            float en = enorm_lds[kt * 16 + fr];
            int kk = kt * 16 + fr;
            #pragma unroll
            for (int r = 0; r < 4; ++r) {
                float m  = aHH[r] + (aHM[r] + aLH[r]);
                float t1 = zn4[r] + en;
                float s  = t1 - 2.0f * m;
                if (s < b1v[r]) { b2v[r] = b1v[r]; b1v[r] = s; b1i[r] = kk; }
                else if (s < b2v[r]) b2v[r] = s;
            }
        }
        __syncthreads();
    }

    // merge best1/best2 across the 16 lanes of each row group
    const int n0w = blk * 64 + wave * 16;
    #pragma unroll
    for (int r = 0; r < 4; ++r) {
        float v1 = b1v[r]; int i1 = b1i[r]; float v2 = b2v[r];
        #pragma unroll
        for (int o = 8; o >= 1; o >>= 1) {
            float ov1 = __shfl_xor(v1, o);
            int   oi1 = __shfl_xor(i1, o);
            float ov2 = __shfl_xor(v2, o);
            bool take = (ov1 < v1) || (ov1 == v1 && oi1 < i1);
            float loser = take ? v1 : ov1;
            if (take) { v1 = ov1; i1 = oi1; }
            v2 = fminf(fminf(v2, ov2), loser);
        }
        if (fr == 0) {
            int n = n0w + fg * 4 + r;
            idx_ws[n] = i1;
            if (v2 - v1 <= TAU) {
                int slot = atomicAdd(nflag, 1);
                worklist[slot] = n;
            }
        }
    }
}

// ---------------- K3: epilogue (zq, loss, idxf, enc ones, counts) ----------------
__global__ __launch_bounds__(256) void k_epilogue(
    const float* __restrict__ z, const float* __restrict__ emb,
    const int* __restrict__ idx_ws,
    float* __restrict__ zq_out, float* __restrict__ idxf_out,
    float* __restrict__ enc, float* __restrict__ loss_row,
    int* __restrict__ counts)
{
    __shared__ int kb[64];
    __shared__ float lpart[4][64];
    const int tid = threadIdx.x;
    const int blk = blockIdx.x;                 // 512
    const int batch = blk >> 4;
    const int p0 = (blk & 15) * 64;
    const int n0 = blk * 64;

    if (tid < 64) {
        int k = idx_ws[n0 + tid];
        kb[tid] = k;
        idxf_out[n0 + tid] = (float)k;
        enc[(size_t)(n0 + tid) * K_CODES + k] = 1.0f;
        atomicAdd(&counts[k], 1);
    }
    __syncthreads();

    int p = tid & 63, dg = tid >> 6;
    const float* zp = z + (size_t)batch * D_DIM * HW + p0 + p;
    float* zqp = zq_out + (size_t)batch * D_DIM * HW + p0 + p;
    const float* er = emb + (size_t)kb[p] * D_DIM;
    float ls = 0.0f;
    for (int d = dg * 64; d < dg * 64 + 64; ++d) {
        float e = er[d];
        float zv = zp[(size_t)d * HW];
        float df = e - zv;
        ls += df * df;
        zqp[(size_t)d * HW] = e;
    }
    lpart[dg][p] = ls;
    __syncthreads();
    if (tid < 64)
        loss_row[n0 + tid] = (lpart[0][tid] + lpart[1][tid]) + (lpart[2][tid] + lpart[3][tid]);
}

// ---------------- K4: exact f64 recheck, one WAVE per flagged row ----------------
// Lane l owns codes k = 64c + l (c=0..15, ascending -> first-min tiebreak).
// z-row kept in 4 regs/lane, broadcast via shuffles. No LDS, no barriers.
__global__ __launch_bounds__(256) void k_recheck(
    const float* __restrict__ z, const float* __restrict__ emb,
    const float* __restrict__ enorm, const float* __restrict__ zn_row,
    const int* __restrict__ worklist, const int* __restrict__ nflag,
    int* __restrict__ idx_ws, int* __restrict__ counts,
    float* __restrict__ loss_row, float* __restrict__ zq_out,
    float* __restrict__ idxf_out, float* __restrict__ enc)
{
    const int tid  = threadIdx.x;
    const int lane = tid & 63, wave = tid >> 6;
    const int gw     = blockIdx.x * 4 + wave;
    const int nwaves = gridDim.x * 4;
    const int nf = *nflag;

    for (int j = gw; j < nf; j += nwaves) {
        const int n = worklist[j];
        const int batch = n >> 10, p = n & (HW - 1);
        const float* zp = z + (size_t)batch * D_DIM * HW + p;

        // z row: lane l holds dims l, l+64, l+128, l+192
        float zr[4];
        #pragma unroll
        for (int i = 0; i < 4; ++i)
            zr[i] = zp[(size_t)(lane + 64 * i) * HW];

        // exact f64 dots for this lane's 16 codes
        double acc[16];
        #pragma unroll
        for (int c = 0; c < 16; ++c) acc[c] = 0.0;
        const float* ebase = emb + (size_t)lane * D_DIM;   // code 64c+l row start - c*64*256
        #pragma unroll
        for (int i = 0; i < 4; ++i) {
            for (int d4 = 0; d4 < 16; ++d4) {
                int sl = d4 * 4;
                double z0 = (double)__shfl(zr[i], sl + 0);
                double z1 = (double)__shfl(zr[i], sl + 1);
                double z2 = (double)__shfl(zr[i], sl + 2);
                double z3 = (double)__shfl(zr[i], sl + 3);
                int doff = i * 64 + sl;
                #pragma unroll
                for (int c = 0; c < 16; ++c) {
                    float4 e = *reinterpret_cast<const float4*>(
                        ebase + (size_t)c * 64 * D_DIM + doff);
                    acc[c] += z0 * (double)e.x + z1 * (double)e.y
                            + z2 * (double)e.z + z3 * (double)e.w;
                }
            }
        }

        // lane-local argmin (quantized score), ascending k
        float bv = 1e30f; int bi = 0;
        {
            #pragma clang fp contract(off)
            float zn = zn_row[n];
            #pragma unroll
            for (int c = 0; c < 16; ++c) {
                int k = c * 64 + lane;
                float mf = (float)acc[c];
                float t1 = zn + enorm[k];
                float s  = t1 - 2.0f * mf;
                if (s < bv) { bv = s; bi = k; }
            }
        }
        // wave merge with first-index tiebreak (all lanes converge)
        #pragma unroll
        for (int o = 32; o >= 1; o >>= 1) {
            float ov = __shfl_xor(bv, o);
            int   oi = __shfl_xor(bi, o);
            if (ov < bv || (ov == bv && oi < bi)) { bv = ov; bi = oi; }
        }
        const int fi = bi;

        // epilogue: zq + loss for this row with the exact winner
        float lsum = 0.0f;
        float* zqp = zq_out + (size_t)batch * D_DIM * HW + p;
        #pragma unroll
        for (int i = 0; i < 4; ++i) {
            float e = emb[(size_t)fi * D_DIM + lane + 64 * i];
            float df = e - zr[i];
            lsum += df * df;
            zqp[(size_t)(lane + 64 * i) * HW] = e;
        }
        #pragma unroll
        for (int o = 32; o >= 1; o >>= 1) lsum += __shfl_xor(lsum, o);

        if (lane == 0) {
            loss_row[n] = lsum;
            int old = idx_ws[n];
            if (old != fi) {
                idx_ws[n] = fi;
                idxf_out[n] = (float)fi;
                enc[(size_t)n * K_CODES + old] = 0.0f;
                enc[(size_t)n * K_CODES + fi] = 1.0f;
                atomicSub(&counts[old], 1);
                atomicAdd(&counts[fi], 1);
            }
        }
    }
}

// ---------------- K5: finalize loss + perplexity ----------------
__global__ void k_final(const float* __restrict__ loss_row,
                        const int* __restrict__ counts,
                        float* __restrict__ out_loss, float* __restrict__ out_perp) {
    __shared__ float la[4], pa[4];
    int tid = threadIdx.x;
    float ls = 0.0f, ps = 0.0f;
    for (int i = tid; i < N_ROWS; i += 256) ls += loss_row[i];
    for (int i = tid; i < K_CODES; i += 256) {
        float em = (float)counts[i] * (1.0f / (float)N_ROWS);
        ps += em * logf(em + 1e-10f);
    }
    #pragma unroll
    for (int off = 32; off > 0; off >>= 1) {
        ls += __shfl_down(ls, off);
        ps += __shfl_down(ps, off);
    }
    if ((tid & 63) == 0) { la[tid >> 6] = ls; pa[tid >> 6] = ps; }
    __syncthreads();
    if (tid == 0) {
        float L = (la[0] + la[1] + la[2] + la[3]) * (1.25f / (float)((size_t)N_ROWS * D_DIM));
        float P = expf(-(pa[0] + pa[1] + pa[2] + pa[3]));
        *out_loss = L;
        *out_perp = P;
    }
}

extern "C" void kernel_launch(void* const* d_in, const int* in_sizes, int n_in,
                              void* d_out, int out_size, void* d_ws, size_t ws_size,
                              hipStream_t stream) {
    const float* z   = (const float*)d_in[0];
    const float* emb = (const float*)d_in[1];
    float* out = (float*)d_out;

    // output layout (floats): loss | z_q_out | perplexity | min_encodings | idx
    float* out_loss = out;
    float* out_zq   = out + 1;
    float* out_perp = out + 1 + (size_t)N_ROWS * D_DIM;
    float* out_enc  = out_perp + 1;
    float* out_idxf = out_enc + (size_t)N_ROWS * K_CODES;

    char* ws = (char*)d_ws;
    int*    idx_ws   = (int*)(ws + 0);           // 131072 B
    int*    counts   = (int*)(ws + 131072);      // 4096 B
    float*  enorm    = (float*)(ws + 135168);    // 4096 B
    float*  loss_row = (float*)(ws + 139264);    // 131072 B
    int*    worklist = (int*)(ws + 270336);      // 131072 B
    int*    nflag    = (int*)(ws + 401408);      // 256 B
    ushort* emb_hi   = (ushort*)(ws + 401664);   // 524288 B
    ushort* emb_lo   = (ushort*)(ws + 925952);   // 524288 B
    float*  zn_row   = (float*)(ws + 1450240);   // 131072 B

    hipMemsetAsync(counts, 0, K_CODES * sizeof(int), stream);
    hipMemsetAsync(nflag, 0, sizeof(int), stream);
    hipMemsetAsync(out_enc, 0, (size_t)N_ROWS * K_CODES * sizeof(float), stream);

    k_emb_cvt<<<256, 256, 0, stream>>>(emb, emb_hi, emb_lo);
    k_emb_norm<<<(K_CODES + 255) / 256, 256, 0, stream>>>(emb, enorm);
    k_screen_mfma<<<512, 256, 0, stream>>>(z, emb_hi, emb_lo, enorm, zn_row,
                                           idx_ws, worklist, nflag);
    k_epilogue<<<512, 256, 0, stream>>>(z, emb, idx_ws, out_zq, out_idxf,
                                        out_enc, loss_row, counts);
    k_recheck<<<512, 256, 0, stream>>>(z, emb, enorm, zn_row, worklist, nflag,
                                       idx_ws, counts, loss_row, out_zq,
                                       out_idxf, out_enc);
    k_final<<<1, 256, 0, stream>>>(loss_row, counts, out_loss, out_perp);
}

// Round 9
// 344.865 us; speedup vs baseline: 1.2519x; 1.2519x over previous
//
#include <hip/hip_runtime.h>
#include <math.h>

#define K_CODES 1024
#define D_DIM   256
#define HW      1024          // 32*32
#define N_ROWS  32768
#define TAU     1.2e-4f       // ambiguity margin (quantized-score domain)

typedef __attribute__((ext_vector_type(8))) short bf16x8;
typedef __attribute__((ext_vector_type(4))) float f32x4;
#define MFMA16(a, b, c) __builtin_amdgcn_mfma_f32_16x16x32_bf16(a, b, c, 0, 0, 0)

__device__ __forceinline__ unsigned bf16_rne_bits(float x) {
    unsigned u = __float_as_uint(x);
    return (u + 0x7FFFu + ((u >> 16) & 1u)) >> 16;
}

// ---------- numpy-faithful pairwise sum of squares (validated round 2) ----------
__device__ __forceinline__ float pw_block128_sq(const float* a) {
    #pragma clang fp contract(off)
    float S[16];
    #pragma unroll
    for (int l = 0; l < 16; ++l) {
        float x0 = a[l],      x4 = a[64 + l];
        float x1 = a[16 + l], x5 = a[80 + l];
        float x2 = a[32 + l], x6 = a[96 + l];
        float x3 = a[48 + l], x7 = a[112 + l];
        float r0 = x0 * x0 + x4 * x4;
        float r1 = x1 * x1 + x5 * x5;
        float r2 = x2 * x2 + x6 * x6;
        float r3 = x3 * x3 + x7 * x7;
        S[l] = (r0 + r1) + (r2 + r3);
    }
    float u0 = S[0] + S[8],  u1 = S[1] + S[9],  u2 = S[2] + S[10], u3 = S[3] + S[11];
    float u4 = S[4] + S[12], u5 = S[5] + S[13], u6 = S[6] + S[14], u7 = S[7] + S[15];
    float v0 = u0 + u4, v1 = u1 + u5, v2 = u2 + u6, v3 = u3 + u7;
    return (v0 + v2) + (v1 + v3);
}
__device__ __forceinline__ float pw_sum256_sq(const float* a) {
    #pragma clang fp contract(off)
    float b0 = pw_block128_sq(a);
    float b1 = pw_block128_sq(a + 128);
    return b0 + b1;
}

// ---------------- K0: emb -> bf16 hi/lo split ----------------
__global__ void k_emb_cvt(const float* __restrict__ emb,
                          ushort* __restrict__ hi, ushort* __restrict__ lo) {
    int i = blockIdx.x * 256 + threadIdx.x;   // 65536 float4 groups
    float4 v = reinterpret_cast<const float4*>(emb)[i];
    ushort4 h, l;
    float x[4] = {v.x, v.y, v.z, v.w};
    ushort hb[4], lb[4];
    #pragma unroll
    for (int j = 0; j < 4; ++j) {
        unsigned hbits = bf16_rne_bits(x[j]);
        float hf = __uint_as_float(hbits << 16);
        unsigned lbits = bf16_rne_bits(x[j] - hf);
        hb[j] = (ushort)hbits; lb[j] = (ushort)lbits;
    }
    h.x = hb[0]; h.y = hb[1]; h.z = hb[2]; h.w = hb[3];
    l.x = lb[0]; l.y = lb[1]; l.z = lb[2]; l.w = lb[3];
    reinterpret_cast<ushort4*>(hi)[i] = h;
    reinterpret_cast<ushort4*>(lo)[i] = l;
}

// ---------------- K1: emb row norms (numpy-faithful) ----------------
__global__ void k_emb_norm(const float* __restrict__ emb, float* __restrict__ enorm) {
    int k = blockIdx.x * 256 + threadIdx.x;
    if (k < K_CODES) enorm[k] = pw_sum256_sq(emb + (size_t)k * D_DIM);
}

// ---------------- K2: MFMA screen ----------------
#define BT_STR 264              // padded ushort stride (16B-aligned rows)
#define BT_BLK (16 * BT_STR)    // one 16-code half-tile (hi or lo)
__global__ __launch_bounds__(256, 2) void k_screen_mfma(
    const float* __restrict__ z,
    const ushort* __restrict__ emb_hi, const ushort* __restrict__ emb_lo,
    const float* __restrict__ enorm, float* __restrict__ zn_row,
    int* __restrict__ idx_ws, int* __restrict__ worklist, int* __restrict__ nflag)
{
    __shared__ __align__(16) float zl[64 * 257];   // 65792 B; reused as B tiles
    __shared__ float enorm_lds[K_CODES];
    __shared__ float zn_sh[64];

    const int tid  = threadIdx.x;
    const int lane = tid & 63, wave = tid >> 6;
    const int blk  = blockIdx.x;                   // 512 blocks
    const int batch = blk >> 4;
    const int p0    = (blk & 15) * 64;
    const float* zb = z + (size_t)batch * D_DIM * HW;

    // stage z tile (f32): zl[p*257 + d] = z[batch][d][p0+p]
    {
        int p = tid & 63;
        for (int d = tid >> 6; d < D_DIM; d += 4)
            zl[p * 257 + d] = zb[(size_t)d * HW + p0 + p];
    }
    // stage enorm
    for (int i = tid; i < K_CODES; i += 256) enorm_lds[i] = enorm[i];
    __syncthreads();

    // numpy-faithful zn per row (also persisted for the recheck kernel)
    if (tid < 64) {
        float zn = pw_sum256_sq(&zl[tid * 257]);
        zn_sh[tid] = zn;
        zn_row[blk * 64 + tid] = zn;
    }

    // build A fragments in registers (hi/lo bf16), 16 rows per wave
    const int fr = lane & 15, fg = lane >> 4;
    bf16x8 Ah[8], Al[8];
    {
        const float* zr = &zl[(wave * 16 + fr) * 257];
        #pragma unroll
        for (int s = 0; s < 8; ++s) {
            int c0 = s * 32 + fg * 8;
            bf16x8 h, l;
            #pragma unroll
            for (int j = 0; j < 8; ++j) {
                float x = zr[c0 + j];
                unsigned hb = bf16_rne_bits(x);
                float hf = __uint_as_float(hb << 16);
                unsigned lb = bf16_rne_bits(x - hf);
                h[j] = (short)hb; l[j] = (short)lb;
            }
            Ah[s] = h; Al[s] = l;
        }
    }
    __syncthreads();   // zl (f32) dead; B tiles may now overwrite it

    ushort* bt = reinterpret_cast<ushort*>(zl);    // [2 buf][hi,lo][16][BT_STR]

    auto stage = [&](int buf, int kt) {
        int row = tid >> 5, d16 = tid & 31;
        #pragma unroll
        for (int i = 0; i < 2; ++i) {
            int r = row + 8 * i;
            size_t src = ((size_t)(kt * 16 + r) << 8) + d16 * 8;
            uint4 vh = *reinterpret_cast<const uint4*>(emb_hi + src);
            uint4 vl = *reinterpret_cast<const uint4*>(emb_lo + src);
            *reinterpret_cast<uint4*>(&bt[(buf * 2 + 0) * BT_BLK + r * BT_STR + d16 * 8]) = vh;
            *reinterpret_cast<uint4*>(&bt[(buf * 2 + 1) * BT_BLK + r * BT_STR + d16 * 8]) = vl;
        }
    };

    float zn4[4];
    #pragma unroll
    for (int r = 0; r < 4; ++r) zn4[r] = zn_sh[wave * 16 + fg * 4 + r];

    float b1v[4] = {1e30f, 1e30f, 1e30f, 1e30f};
    float b2v[4] = {1e30f, 1e30f, 1e30f, 1e30f};
    int   b1i[4] = {0, 0, 0, 0};

    stage(0, 0);
    __syncthreads();

    const int boff = fr * BT_STR + fg * 8;
    for (int kt = 0; kt < 64; ++kt) {
        int cur = kt & 1;
        if (kt < 63) stage(cur ^ 1, kt + 1);

        f32x4 aHH = {0.f, 0.f, 0.f, 0.f};
        f32x4 aHM = {0.f, 0.f, 0.f, 0.f};
        f32x4 aLH = {0.f, 0.f, 0.f, 0.f};
        const ushort* bhp = bt + cur * 2 * BT_BLK + boff;
        const ushort* blp = bhp + BT_BLK;
        #pragma unroll
        for (int s = 0; s < 8; ++s) {
            bf16x8 Bh = *reinterpret_cast<const bf16x8*>(bhp + s * 32);
            bf16x8 Bl = *reinterpret_cast<const bf16x8*>(blp + s * 32);
            aHH = MFMA16(Ah[s], Bh, aHH);
            aHM = MFMA16(Ah[s], Bl, aHM);
            aLH = MFMA16(Al[s], Bh, aLH);
        }
        {
            #pragma clang fp contract(off)
            float en = enorm_lds[kt * 16 + fr];
            int kk = kt * 16 + fr;
            #pragma unroll
            for (int r = 0; r < 4; ++r) {
                float m  = aHH[r] + (aHM[r] + aLH[r]);
                float t1 = zn4[r] + en;
                float s  = t1 - 2.0f * m;
                if (s < b1v[r]) { b2v[r] = b1v[r]; b1v[r] = s; b1i[r] = kk; }
                else if (s < b2v[r]) b2v[r] = s;
            }
        }
        __syncthreads();
    }

    // merge best1/best2 across the 16 lanes of each row group
    const int n0w = blk * 64 + wave * 16;
    #pragma unroll
    for (int r = 0; r < 4; ++r) {
        float v1 = b1v[r]; int i1 = b1i[r]; float v2 = b2v[r];
        #pragma unroll
        for (int o = 8; o >= 1; o >>= 1) {
            float ov1 = __shfl_xor(v1, o);
            int   oi1 = __shfl_xor(i1, o);
            float ov2 = __shfl_xor(v2, o);
            bool take = (ov1 < v1) || (ov1 == v1 && oi1 < i1);
            float loser = take ? v1 : ov1;
            if (take) { v1 = ov1; i1 = oi1; }
            v2 = fminf(fminf(v2, ov2), loser);
        }
        if (fr == 0) {
            int n = n0w + fg * 4 + r;
            idx_ws[n] = i1;
            if (v2 - v1 <= TAU) {
                int slot = atomicAdd(nflag, 1);
                worklist[slot] = n;
            }
        }
    }
}

// ---------------- K3: epilogue (zq, loss, idxf, enc ones, counts) ----------------
__global__ __launch_bounds__(256) void k_epilogue(
    const float* __restrict__ z, const float* __restrict__ emb,
    const int* __restrict__ idx_ws,
    float* __restrict__ zq_out, float* __restrict__ idxf_out,
    float* __restrict__ enc, float* __restrict__ loss_row,
    int* __restrict__ counts)
{
    __shared__ int kb[64];
    __shared__ float lpart[4][64];
    const int tid = threadIdx.x;
    const int blk = blockIdx.x;                 // 512
    const int batch = blk >> 4;
    const int p0 = (blk & 15) * 64;
    const int n0 = blk * 64;

    if (tid < 64) {
        int k = idx_ws[n0 + tid];
        kb[tid] = k;
        idxf_out[n0 + tid] = (float)k;
        enc[(size_t)(n0 + tid) * K_CODES + k] = 1.0f;
        atomicAdd(&counts[k], 1);
    }
    __syncthreads();

    int p = tid & 63, dg = tid >> 6;
    const float* zp = z + (size_t)batch * D_DIM * HW + p0 + p;
    float* zqp = zq_out + (size_t)batch * D_DIM * HW + p0 + p;
    const float* er = emb + (size_t)kb[p] * D_DIM;
    float ls = 0.0f;
    for (int d = dg * 64; d < dg * 64 + 64; ++d) {
        float e = er[d];
        float zv = zp[(size_t)d * HW];
        float df = e - zv;
        ls += df * df;
        zqp[(size_t)d * HW] = e;
    }
    lpart[dg][p] = ls;
    __syncthreads();
    if (tid < 64)
        loss_row[n0 + tid] = (lpart[0][tid] + lpart[1][tid]) + (lpart[2][tid] + lpart[3][tid]);
}

// ---------------- K4: exact f64 recheck — 8 rows per block, LDS-staged emb ----------------
// Thread (r,c) = (tid>>5, tid&31): row r of chunk, code c within a 32-code tile.
// emb tiles double-buffered in LDS (coalesced staging); per-thread ascending-k
// argmin over quantized f32 scores; fixes outputs ONLY when winner changes.
#define RCHUNK 8
#define ET_STR 260   // f32 stride: %4==0 (float4 aligned), %32==4 (mild conflict)
__global__ __launch_bounds__(256, 2) void k_recheck(
    const float* __restrict__ z, const float* __restrict__ emb,
    const float* __restrict__ enorm, const float* __restrict__ zn_row,
    const int* __restrict__ worklist, const int* __restrict__ nflag,
    int* __restrict__ idx_ws, int* __restrict__ counts,
    float* __restrict__ loss_row, float* __restrict__ zq_out,
    float* __restrict__ idxf_out, float* __restrict__ enc)
{
    __shared__ __align__(16) float etile[2][32 * ET_STR];   // 66.6 KB
    __shared__ __align__(16) float zrows[RCHUNK][ET_STR];
    __shared__ float en_lds[K_CODES];
    __shared__ int   nrow_sh[RCHUNK];

    const int tid = threadIdx.x;
    const int nf  = *nflag;
    const int r   = tid >> 5, c = tid & 31;

    for (int i = tid; i < K_CODES; i += 256) en_lds[i] = enorm[i];

    auto stage = [&](int buf, int kt) {
        int sc = tid >> 3, q = tid & 7;    // 8 consecutive threads cover one code row
        const float* src = emb + (size_t)(kt * 32 + sc) * D_DIM + q * 32;
        float* dst = &etile[buf][sc * ET_STR + q * 32];
        #pragma unroll
        for (int j = 0; j < 8; ++j)
            *reinterpret_cast<float4*>(dst + j * 4) =
                *reinterpret_cast<const float4*>(src + j * 4);
    };

    for (int chunk = blockIdx.x; chunk * RCHUNK < nf; chunk += gridDim.x) {
        if (tid < RCHUNK) {
            int j = chunk * RCHUNK + tid;
            nrow_sh[tid] = (j < nf) ? worklist[j] : -1;
        }
        __syncthreads();
        const int n = nrow_sh[r];
        const bool active = (n >= 0);
        if (active) {
            int batch = n >> 10, p = n & (HW - 1);
            const float* zp = z + (size_t)batch * D_DIM * HW + p;
            for (int d = c; d < D_DIM; d += 32)
                zrows[r][d] = zp[(size_t)d * HW];
        }
        stage(0, 0);
        __syncthreads();

        const float znr = active ? zn_row[n] : 0.0f;
        float bv = 1e30f; int bi = 0;

        for (int kt = 0; kt < 32; ++kt) {
            int cur = kt & 1;
            if (kt < 31) stage(cur ^ 1, kt + 1);

            const float* er = &etile[cur][c * ET_STR];
            const float* zr = &zrows[r][0];
            double a0 = 0.0, a1 = 0.0, a2 = 0.0, a3 = 0.0;
            #pragma unroll 4
            for (int d = 0; d < D_DIM; d += 4) {
                float4 e4 = *reinterpret_cast<const float4*>(er + d);
                float4 z4 = *reinterpret_cast<const float4*>(zr + d);
                a0 += (double)z4.x * (double)e4.x;
                a1 += (double)z4.y * (double)e4.y;
                a2 += (double)z4.z * (double)e4.z;
                a3 += (double)z4.w * (double)e4.w;
            }
            {
                #pragma clang fp contract(off)
                float mf = (float)((a0 + a1) + (a2 + a3));
                int k = kt * 32 + c;
                float t1 = znr + en_lds[k];
                float s  = t1 - 2.0f * mf;
                if (s < bv) { bv = s; bi = k; }   // ascending k per thread
            }
            __syncthreads();
        }

        // merge across the 32 threads of this row (first-index tiebreak)
        #pragma unroll
        for (int o = 16; o >= 1; o >>= 1) {
            float ov = __shfl_xor(bv, o);
            int   oi = __shfl_xor(bi, o);
            if (ov < bv || (ov == bv && oi < bi)) { bv = ov; bi = oi; }
        }

        if (active) {
            int old = idx_ws[n];           // same address across the 32 lanes
            if (old != bi) {
                int batch = n >> 10, p = n & (HW - 1);
                const float* erow = emb + (size_t)bi * D_DIM;
                float* zqp = zq_out + (size_t)batch * D_DIM * HW + p;
                float lsum = 0.0f;
                for (int d = c; d < D_DIM; d += 32) {
                    float e = erow[d];
                    float df = e - zrows[r][d];
                    lsum += df * df;
                    zqp[(size_t)d * HW] = e;
                }
                #pragma unroll
                for (int o = 16; o >= 1; o >>= 1) lsum += __shfl_xor(lsum, o);
                if (c == 0) {
                    loss_row[n] = lsum;
                    idx_ws[n] = bi;
                    idxf_out[n] = (float)bi;
                    enc[(size_t)n * K_CODES + old] = 0.0f;
                    enc[(size_t)n * K_CODES + bi] = 1.0f;
                    atomicSub(&counts[old], 1);
                    atomicAdd(&counts[bi], 1);
                }
            }
        }
        __syncthreads();   // protect zrows/nrow_sh before next chunk
    }
}

// ---------------- K5: finalize loss + perplexity ----------------
__global__ void k_final(const float* __restrict__ loss_row,
                        const int* __restrict__ counts,
                        float* __restrict__ out_loss, float* __restrict__ out_perp) {
    __shared__ float la[4], pa[4];
    int tid = threadIdx.x;
    float ls = 0.0f, ps = 0.0f;
    for (int i = tid; i < N_ROWS; i += 256) ls += loss_row[i];
    for (int i = tid; i < K_CODES; i += 256) {
        float em = (float)counts[i] * (1.0f / (float)N_ROWS);
        ps += em * logf(em + 1e-10f);
    }
    #pragma unroll
    for (int off = 32; off > 0; off >>= 1) {
        ls += __shfl_down(ls, off);
        ps += __shfl_down(ps, off);
    }
    if ((tid & 63) == 0) { la[tid >> 6] = ls; pa[tid >> 6] = ps; }
    __syncthreads();
    if (tid == 0) {
        float L = (la[0] + la[1] + la[2] + la[3]) * (1.25f / (float)((size_t)N_ROWS * D_DIM));
        float P = expf(-(pa[0] + pa[1] + pa[2] + pa[3]));
        *out_loss = L;
        *out_perp = P;
    }
}

extern "C" void kernel_launch(void* const* d_in, const int* in_sizes, int n_in,
                              void* d_out, int out_size, void* d_ws, size_t ws_size,
                              hipStream_t stream) {
    const float* z   = (const float*)d_in[0];
    const float* emb = (const float*)d_in[1];
    float* out = (float*)d_out;

    // output layout (floats): loss | z_q_out | perplexity | min_encodings | idx
    float* out_loss = out;
    float* out_zq   = out + 1;
    float* out_perp = out + 1 + (size_t)N_ROWS * D_DIM;
    float* out_enc  = out_perp + 1;
    float* out_idxf = out_enc + (size_t)N_ROWS * K_CODES;

    char* ws = (char*)d_ws;
    int*    idx_ws   = (int*)(ws + 0);           // 131072 B
    int*    counts   = (int*)(ws + 131072);      // 4096 B
    float*  enorm    = (float*)(ws + 135168);    // 4096 B
    float*  loss_row = (float*)(ws + 139264);    // 131072 B
    int*    worklist = (int*)(ws + 270336);      // 131072 B
    int*    nflag    = (int*)(ws + 401408);      // 256 B
    ushort* emb_hi   = (ushort*)(ws + 401664);   // 524288 B
    ushort* emb_lo   = (ushort*)(ws + 925952);   // 524288 B
    float*  zn_row   = (float*)(ws + 1450240);   // 131072 B

    hipMemsetAsync(counts, 0, K_CODES * sizeof(int), stream);
    hipMemsetAsync(nflag, 0, sizeof(int), stream);
    hipMemsetAsync(out_enc, 0, (size_t)N_ROWS * K_CODES * sizeof(float), stream);

    k_emb_cvt<<<256, 256, 0, stream>>>(emb, emb_hi, emb_lo);
    k_emb_norm<<<(K_CODES + 255) / 256, 256, 0, stream>>>(emb, enorm);
    k_screen_mfma<<<512, 256, 0, stream>>>(z, emb_hi, emb_lo, enorm, zn_row,
                                           idx_ws, worklist, nflag);
    k_epilogue<<<512, 256, 0, stream>>>(z, emb, idx_ws, out_zq, out_idxf,
                                        out_enc, loss_row, counts);
    k_recheck<<<256, 256, 0, stream>>>(z, emb, enorm, zn_row, worklist, nflag,
                                       idx_ws, counts, loss_row, out_zq,
                                       out_idxf, out_enc);
    k_final<<<1, 256, 0, stream>>>(loss_row, counts, out_loss, out_perp);
}